// Round 8
// baseline (555.634 us; speedup 1.0000x reference)
//
#include <hip/hip_runtime.h>
#include <hip/hip_bf16.h>
#include <math.h>

typedef __attribute__((ext_vector_type(8))) short bf16x8;
typedef __attribute__((ext_vector_type(4))) float f32x4;
typedef unsigned short u16;
typedef unsigned int u32;

__device__ __forceinline__ u32 bf16_rne(float f) {
  u32 u = __float_as_uint(f);
  return (u + 0x7FFFu + ((u >> 16) & 1u)) >> 16;
}
__device__ __forceinline__ float bf16_val(u32 b) { return __uint_as_float(b << 16); }

// split 8 consecutive floats into bf16 hi/lo fragments
__device__ __forceinline__ void split8(const float* src, bf16x8& h, bf16x8& l) {
  float4 f0 = *(const float4*)src;
  float4 f1 = *(const float4*)(src + 4);
  float f[8] = {f0.x, f0.y, f0.z, f0.w, f1.x, f1.y, f1.z, f1.w};
#pragma unroll
  for (int i = 0; i < 8; ++i) {
    u32 hb = bf16_rne(f[i]);
    u32 lb = bf16_rne(f[i] - bf16_val(hb));
    h[i] = (short)hb;
    l[i] = (short)lb;
  }
}

// ---- transpose each 256x256 fp32 slice, split into interleaved hi/lo ----
// out layout: [z][2][256][256]  ([e][d], hi then lo)
__global__ void split_transpose256(const float* __restrict__ in, u16* __restrict__ out) {
  __shared__ float tile[32][33];
  const size_t zin = (size_t)blockIdx.z * 65536;
  const size_t zout = (size_t)blockIdx.z * 131072;
  const int tx = threadIdx.x, ty = threadIdx.y;
#pragma unroll
  for (int i = 0; i < 4; ++i) {
    int y = blockIdx.y * 32 + ty + i * 8;
    int x = blockIdx.x * 32 + tx;
    tile[ty + i * 8][tx] = in[zin + (size_t)y * 256 + x];
  }
  __syncthreads();
#pragma unroll
  for (int i = 0; i < 4; ++i) {
    float v = tile[tx][ty + i * 8];
    u32 hb = bf16_rne(v);
    u32 lb = bf16_rne(v - bf16_val(hb));
    size_t idx = (size_t)(blockIdx.x * 32 + ty + i * 8) * 256 + blockIdx.y * 32 + tx;
    out[zout + idx] = (u16)hb;
    out[zout + 65536 + idx] = (u16)lb;
  }
}

// ---------------- associativity-collapsed capsule routing ----------------
// Routing never materializes P:  s = (p^T A) W,  dlogit = A (W v).
// Block = (kk, group of 8 a).  512 threads = 8 waves; wave w <-> capsule a0+w
// for the per-capsule passes; waves cooperate (split over N) for the W-GEMMs.
// blockIdx&7 = a-group (XCD-pinned for L2 residency of A), blockIdx>>3 = kk.
template <int R>
__global__ __launch_bounds__(512, 4) void caps_assoc(
    const float* __restrict__ Afp,   // [64][R][256] fp32  (x or out1)
    const float* __restrict__ Wfp,   // [KN][256][256] fp32 native [d][e]
    const u16* __restrict__ Wts,     // [KN][2][256][256] split, transposed [e][d]
    float* __restrict__ outp,        // stage1: out1 [64][KN][256]; stage2: out [KN][64][256]
    int KN, int stage) {
  constexpr int MT = R / 16;
  __shared__ float pP[8][R];                       // probs
  __shared__ float pL[8][R];                       // logits
  __shared__ __align__(16) float yB[8][256];       // y = p^T A
  __shared__ __align__(16) float vB[8][256];       // v = g*s
  __shared__ __align__(16) float wvB[8][256];      // wv = W v
  __shared__ float ssred[8][16];
  __shared__ float gB[16];

  const int tid = threadIdx.x;
  const int w = tid >> 6, lane = tid & 63, q = lane >> 4, li = lane & 15;
  const int grp = blockIdx.x & 7;
  const int kk = blockIdx.x >> 3;
  const int a0 = grp * 8;

  const float* Aw = Afp + (size_t)(a0 + w) * R * 256;   // this wave's capsule A
  const float* Wn = Wfp + (size_t)kk * 65536;
  const u16* Wth = Wts + (size_t)kk * 131072;           // hi; +65536 = lo

  // init probs uniform, logits zero
  for (int i = tid; i < 8 * R; i += 512) {
    (&pP[0][0])[i] = 1.0f / R;
    (&pL[0][0])[i] = 0.f;
  }
  __syncthreads();

  for (int iter = 0; iter < 3; ++iter) {
    // ---- Phase Y: y[w][d] = sum_b p[w][b] * A[b][d]  (pure fp32) ----
    {
      float4 ya = {0.f, 0.f, 0.f, 0.f};
#pragma unroll 8
      for (int b = 0; b < R; ++b) {
        float pb = pP[w][b];
        float4 xa = *(const float4*)(Aw + b * 256 + lane * 4);
        ya.x += pb * xa.x; ya.y += pb * xa.y; ya.z += pb * xa.z; ya.w += pb * xa.w;
      }
      *(float4*)&yB[w][lane * 4] = ya;
    }
    __syncthreads();   // (A)

    // ---- Phase S: s = y W  via MFMA, wave w owns e-cols [w*32, w*32+32) ----
    f32x4 sacc[2] = {};
    for (int ks = 0; ks < 8; ++ks) {
      const int k0 = ks * 32;
      bf16x8 yh = {}, yl = {};
      if (li < 8) split8(&yB[li][k0 + q * 8], yh, yl);
#pragma unroll
      for (int nt = 0; nt < 2; ++nt) {
        int e = w * 32 + nt * 16 + li;
        const u16* bp = Wth + e * 256 + k0 + q * 8;
        bf16x8 bh = *(const bf16x8*)bp;
        bf16x8 bl = *(const bf16x8*)(bp + 65536);
        sacc[nt] = __builtin_amdgcn_mfma_f32_16x16x32_bf16(yl, bh, sacc[nt], 0, 0, 0);
        sacc[nt] = __builtin_amdgcn_mfma_f32_16x16x32_bf16(yh, bl, sacc[nt], 0, 0, 0);
        sacc[nt] = __builtin_amdgcn_mfma_f32_16x16x32_bf16(yh, bh, sacc[nt], 0, 0, 0);
      }
    }
    // ss[j] = sum_e s[j][e]^2 : per-lane over nt, butterfly over li, LDS over waves
#pragma unroll
    for (int r = 0; r < 4; ++r) {
      float t = sacc[0][r] * sacc[0][r] + sacc[1][r] * sacc[1][r];
      t += __shfl_xor(t, 1);
      t += __shfl_xor(t, 2);
      t += __shfl_xor(t, 4);
      t += __shfl_xor(t, 8);
      if (li == 0) ssred[w][q * 4 + r] = t;
    }
    __syncthreads();   // (B)
    if (tid < 16) {
      float ss = ssred[0][tid] + ssred[1][tid] + ssred[2][tid] + ssred[3][tid] +
                 ssred[4][tid] + ssred[5][tid] + ssred[6][tid] + ssred[7][tid];
      gB[tid] = (ss > 0.f) ? sqrtf(ss) / (1.0f + ss) : 0.f;   // v = g * s
    }
    __syncthreads();   // (C)

    if (iter == 2) {
      // ---- final output: out = g * s ----
#pragma unroll
      for (int nt = 0; nt < 2; ++nt)
#pragma unroll
        for (int r = 0; r < 4; ++r) {
          int j = q * 4 + r;
          if (j < 8) {
            int e = w * 32 + nt * 16 + li;
            float val = gB[j] * sacc[nt][r];
            size_t ob = (stage == 1)
                ? ((size_t)(a0 + j) * KN + kk) * 256 + e
                : ((size_t)kk * 64 + (a0 + j)) * 256 + e;
            outp[ob] = val;
          }
        }
      return;
    }

    // ---- v = g*s -> LDS ----
#pragma unroll
    for (int nt = 0; nt < 2; ++nt)
#pragma unroll
      for (int r = 0; r < 4; ++r) {
        int j = q * 4 + r;
        if (j < 8) vB[j][w * 32 + nt * 16 + li] = gB[j] * sacc[nt][r];
      }
    __syncthreads();   // (D)

    // ---- Phase WV: wv = W v  (contract over e; B from native W, split on fly) ----
    {
      f32x4 wacc[2] = {};
      for (int ks = 0; ks < 8; ++ks) {
        const int k0 = ks * 32;   // k = e
        bf16x8 vh = {}, vl = {};
        if (li < 8) split8(&vB[li][k0 + q * 8], vh, vl);
#pragma unroll
        for (int nt = 0; nt < 2; ++nt) {
          int d = w * 32 + nt * 16 + li;
          bf16x8 bh, bl;
          split8(Wn + d * 256 + k0 + q * 8, bh, bl);
          wacc[nt] = __builtin_amdgcn_mfma_f32_16x16x32_bf16(vl, bh, wacc[nt], 0, 0, 0);
          wacc[nt] = __builtin_amdgcn_mfma_f32_16x16x32_bf16(vh, bl, wacc[nt], 0, 0, 0);
          wacc[nt] = __builtin_amdgcn_mfma_f32_16x16x32_bf16(vh, bh, wacc[nt], 0, 0, 0);
        }
      }
#pragma unroll
      for (int nt = 0; nt < 2; ++nt)
#pragma unroll
        for (int r = 0; r < 4; ++r) {
          int j = q * 4 + r;
          if (j < 8) wvB[j][w * 32 + nt * 16 + li] = wacc[nt][r];
        }
    }
    __syncthreads();   // (E)

    // ---- Phase DL: dlogit = A * wv  (per-wave capsule; N=1 MFMA column) ----
    {
      f32x4 dacc[MT] = {};
      for (int ks = 0; ks < 8; ++ks) {
        const int k0 = ks * 32;   // k = d
        bf16x8 bh = {}, bl = {};
        if (li == 0) split8(&wvB[w][k0 + q * 8], bh, bl);
#pragma unroll
        for (int mt = 0; mt < MT; ++mt) {
          bf16x8 ah, al;
          split8(Aw + (mt * 16 + li) * 256 + k0 + q * 8, ah, al);
          dacc[mt] = __builtin_amdgcn_mfma_f32_16x16x32_bf16(al, bh, dacc[mt], 0, 0, 0);
          dacc[mt] = __builtin_amdgcn_mfma_f32_16x16x32_bf16(ah, bl, dacc[mt], 0, 0, 0);
          dacc[mt] = __builtin_amdgcn_mfma_f32_16x16x32_bf16(ah, bh, dacc[mt], 0, 0, 0);
        }
      }
      if (li == 0) {
#pragma unroll
        for (int mt = 0; mt < MT; ++mt)
#pragma unroll
          for (int r = 0; r < 4; ++r)
            pL[w][mt * 16 + q * 4 + r] += dacc[mt][r];
      }
    }

    // ---- softmax over R logits (wave w on its own row; intra-wave dep only) ----
    {
      float l0 = pL[w][lane];
      float l1 = (R == 128) ? pL[w][lane + 64] : -3.0e38f;
      float m = fmaxf(l0, l1);
#pragma unroll
      for (int d2 = 1; d2 < 64; d2 <<= 1) m = fmaxf(m, __shfl_xor(m, d2));
      float e0 = expf(l0 - m);
      float e1 = (R == 128) ? expf(l1 - m) : 0.f;
      float zz = e0 + e1;
#pragma unroll
      for (int d2 = 1; d2 < 64; d2 <<= 1) zz += __shfl_xor(zz, d2);
      float inv = 1.0f / zz;
      pP[w][lane] = e0 * inv;
      if (R == 128) pP[w][lane + 64] = e1 * inv;
    }
    // no barrier needed: next phase-Y only touches this wave's own rows, and
    // cross-wave buffers are fenced by barriers A-E of the next iteration.
  }
}

extern "C" void kernel_launch(void* const* d_in, const int* in_sizes, int n_in,
                              void* d_out, int out_size, void* d_ws, size_t ws_size,
                              hipStream_t stream) {
  const float* x  = (const float*)d_in[0];   // [64][128][256]
  const float* w1 = (const float*)d_in[1];   // [64][256][256]
  const float* wc = (const float*)d_in[2];   // [32][256][256]
  float* out = (float*)d_out;                // [32][64][256]

  char* ws = (char*)d_ws;
  u16*   w1T = (u16*)(ws);                   // [64][2][256][256] split-T  16 MB
  u16*   wcT = (u16*)(ws + (16u << 20));     // [32][2][256][256] split-T   8 MB
  float* o1f = (float*)(ws + (24u << 20));   // [64][64][256] fp32          4 MB

  split_transpose256<<<dim3(8, 8, 64), dim3(32, 8), 0, stream>>>(w1, w1T);
  split_transpose256<<<dim3(8, 8, 32), dim3(32, 8), 0, stream>>>(wc, wcT);
  caps_assoc<128><<<512, 512, 0, stream>>>(x, w1, w1T, o1f, 64, 1);
  caps_assoc<64><<<256, 512, 0, stream>>>(o1f, wc, wcT, out, 32, 2);
}

// Round 9
// 412.935 us; speedup vs baseline: 1.3456x; 1.3456x over previous
//
#include <hip/hip_runtime.h>
#include <hip/hip_bf16.h>
#include <math.h>

typedef __attribute__((ext_vector_type(8))) short bf16x8;
typedef __attribute__((ext_vector_type(4))) float f32x4;
typedef unsigned short u16;
typedef unsigned int u32;

__device__ __forceinline__ u32 bf16_rne(float f) {
  u32 u = __float_as_uint(f);
  return (u + 0x7FFFu + ((u >> 16) & 1u)) >> 16;
}
__device__ __forceinline__ float bf16_val(u32 b) { return __uint_as_float(b << 16); }

__device__ __forceinline__ void split8(const float* s, bf16x8& h, bf16x8& l) {
  float4 f0 = *(const float4*)s;
  float4 f1 = *(const float4*)(s + 4);
  float ff[8] = {f0.x, f0.y, f0.z, f0.w, f1.x, f1.y, f1.z, f1.w};
#pragma unroll
  for (int i = 0; i < 8; ++i) {
    u32 hb = bf16_rne(ff[i]);
    u32 lb = bf16_rne(ff[i] - bf16_val(hb));
    h[i] = (short)hb;
    l[i] = (short)lb;
  }
}

__device__ __forceinline__ f32x4 mfma(bf16x8 a, bf16x8 b, f32x4 c) {
  return __builtin_amdgcn_mfma_f32_16x16x32_bf16(a, b, c, 0, 0, 0);
}

// ---- split fp32 -> [blk][2][chunkElems] bf16 hi/lo (native layout) ----
__global__ void split_pairs(const float* __restrict__ in, u16* __restrict__ out,
                            int n4, int chunk4) {
  int i = blockIdx.x * 256 + threadIdx.x;
  if (i >= n4) return;
  float4 v = ((const float4*)in)[i];
  u32 h0 = bf16_rne(v.x), h1 = bf16_rne(v.y), h2 = bf16_rne(v.z), h3 = bf16_rne(v.w);
  u32 l0 = bf16_rne(v.x - bf16_val(h0));
  u32 l1 = bf16_rne(v.y - bf16_val(h1));
  u32 l2 = bf16_rne(v.z - bf16_val(h2));
  u32 l3 = bf16_rne(v.w - bf16_val(h3));
  ushort4 hv; hv.x = (u16)h0; hv.y = (u16)h1; hv.z = (u16)h2; hv.w = (u16)h3;
  ushort4 lv; lv.x = (u16)l0; lv.y = (u16)l1; lv.z = (u16)l2; lv.w = (u16)l3;
  int blk = i / chunk4, off = i % chunk4;
  ((ushort4*)out)[(size_t)blk * 2 * chunk4 + off] = hv;
  ((ushort4*)out)[(size_t)blk * 2 * chunk4 + chunk4 + off] = lv;
}

// ---- transpose each 256x256 fp32 slice, split hi/lo: out [z][2][256][256] ----
__global__ void split_transpose256(const float* __restrict__ in, u16* __restrict__ out) {
  __shared__ float tile[32][33];
  const size_t zin = (size_t)blockIdx.z * 65536;
  const size_t zout = (size_t)blockIdx.z * 131072;
  const int tx = threadIdx.x, ty = threadIdx.y;
#pragma unroll
  for (int i = 0; i < 4; ++i) {
    int y = blockIdx.y * 32 + ty + i * 8;
    int x = blockIdx.x * 32 + tx;
    tile[ty + i * 8][tx] = in[zin + (size_t)y * 256 + x];
  }
  __syncthreads();
#pragma unroll
  for (int i = 0; i < 4; ++i) {
    float v = tile[tx][ty + i * 8];
    u32 hb = bf16_rne(v);
    u32 lb = bf16_rne(v - bf16_val(hb));
    size_t idx = (size_t)(blockIdx.x * 32 + ty + i * 8) * 256 + blockIdx.y * 32 + tx;
    out[zout + idx] = (u16)hb;
    out[zout + 65536 + idx] = (u16)lb;
  }
}

// ---- per-z transpose [Rr][256] -> split [z][2][256][Rr] ----
__global__ void split_transpose_rect(const float* __restrict__ in, u16* __restrict__ out,
                                     int Rr) {
  __shared__ float tile[32][33];
  const size_t zin = (size_t)blockIdx.z * Rr * 256;
  const size_t zout = (size_t)blockIdx.z * 2 * 256 * Rr;
  const int tx = threadIdx.x, ty = threadIdx.y;
#pragma unroll
  for (int i = 0; i < 4; ++i) {
    int y = blockIdx.y * 32 + ty + i * 8;   // row b
    int x = blockIdx.x * 32 + tx;           // col d
    tile[ty + i * 8][tx] = in[zin + (size_t)y * 256 + x];
  }
  __syncthreads();
#pragma unroll
  for (int i = 0; i < 4; ++i) {
    float v = tile[tx][ty + i * 8];
    u32 hb = bf16_rne(v);
    u32 lb = bf16_rne(v - bf16_val(hb));
    int d = blockIdx.x * 32 + ty + i * 8;
    int b = blockIdx.y * 32 + tx;
    size_t idx = zout + (size_t)d * Rr + b;
    out[idx] = (u16)hb;
    out[idx + (size_t)256 * Rr] = (u16)lb;
  }
}

// ---- y0[a][d] = scale * sum_b A[a][b][d] ----
__global__ void mean_rows(const float* __restrict__ A, float* __restrict__ y0,
                          int Rr, float scale) {
  int a = blockIdx.x, d = threadIdx.x;
  const float* p = A + (size_t)a * Rr * 256 + d;
  float s = 0.f;
  for (int b = 0; b < Rr; ++b) s += p[(size_t)b * 256];
  y0[a * 256 + d] = s * scale;
}

// ================= pswv: block = kk =================
// Phase S: s[a,e] = sum_d y[a,d]*Wt[e,d]  (MFMA m=a(4mt), n=e; wave = e-quarter)
// squash -> v; iter==2: write final out; else v->LDS, Phase WV:
// wv[a,d] = sum_e v[a,e]*W[d,e]  (wave = d-quarter) -> global wv[a][KN][256]
template <int KN>
__global__ __launch_bounds__(256, 2) void pswv(
    const float* __restrict__ Y, const float* __restrict__ y0,
    const u16* __restrict__ Wts, const u16* __restrict__ Wns,
    float* __restrict__ wv, float* __restrict__ outb,
    int iter, int stage) {
  __shared__ __align__(16) float vL[64 * 260];
  __shared__ float ssp[4][64];
  __shared__ float gG[64];
  const int tid = threadIdx.x;
  const int w = tid >> 6, lane = tid & 63, q = lane >> 4, li = lane & 15;
  const int kk = blockIdx.x;

  f32x4 acc[4][4] = {};
  for (int ks = 0; ks < 8; ++ks) {
    const int d0 = ks * 32 + q * 8;
    bf16x8 ah[4], al[4];
#pragma unroll
    for (int mt = 0; mt < 4; ++mt) {
      int a = mt * 16 + li;
      const float* ys = (iter == 0) ? (y0 + a * 256 + d0)
                                    : (Y + ((size_t)kk * 64 + a) * 256 + d0);
      split8(ys, ah[mt], al[mt]);
    }
#pragma unroll
    for (int nt = 0; nt < 4; ++nt) {
      int e = w * 64 + nt * 16 + li;
      const u16* bp = Wts + (size_t)kk * 131072 + (size_t)e * 256 + d0;
      bf16x8 bh = *(const bf16x8*)bp;
      bf16x8 bl = *(const bf16x8*)(bp + 65536);
#pragma unroll
      for (int mt = 0; mt < 4; ++mt) {
        acc[mt][nt] = mfma(al[mt], bh, acc[mt][nt]);
        acc[mt][nt] = mfma(ah[mt], bl, acc[mt][nt]);
        acc[mt][nt] = mfma(ah[mt], bh, acc[mt][nt]);
      }
    }
  }
  // squash scale per a
#pragma unroll
  for (int mt = 0; mt < 4; ++mt) {
#pragma unroll
    for (int r = 0; r < 4; ++r) {
      float t = acc[mt][0][r] * acc[mt][0][r] + acc[mt][1][r] * acc[mt][1][r] +
                acc[mt][2][r] * acc[mt][2][r] + acc[mt][3][r] * acc[mt][3][r];
      t += __shfl_xor(t, 1);
      t += __shfl_xor(t, 2);
      t += __shfl_xor(t, 4);
      t += __shfl_xor(t, 8);
      if (li == 0) ssp[w][mt * 16 + q * 4 + r] = t;
    }
  }
  __syncthreads();
  if (tid < 64) {
    float ss = ssp[0][tid] + ssp[1][tid] + ssp[2][tid] + ssp[3][tid];
    gG[tid] = (ss > 0.f) ? sqrtf(ss) / (1.0f + ss) : 0.f;
  }
  __syncthreads();

  if (iter == 2) {
#pragma unroll
    for (int mt = 0; mt < 4; ++mt)
#pragma unroll
      for (int r = 0; r < 4; ++r) {
        int a = mt * 16 + q * 4 + r;
        float g = gG[a];
#pragma unroll
        for (int nt = 0; nt < 4; ++nt) {
          int e = w * 64 + nt * 16 + li;
          size_t ob = (stage == 1) ? ((size_t)a * KN + kk) * 256 + e
                                   : ((size_t)kk * 64 + a) * 256 + e;
          outb[ob] = g * acc[mt][nt][r];
        }
      }
    return;
  }
  // v -> LDS
#pragma unroll
  for (int mt = 0; mt < 4; ++mt)
#pragma unroll
    for (int r = 0; r < 4; ++r) {
      int a = mt * 16 + q * 4 + r;
      float g = gG[a];
#pragma unroll
      for (int nt = 0; nt < 4; ++nt)
        vL[a * 260 + w * 64 + nt * 16 + li] = g * acc[mt][nt][r];
    }
  __syncthreads();
  // Phase WV
  f32x4 wacc[4][4] = {};
  for (int ks = 0; ks < 8; ++ks) {
    const int e0 = ks * 32 + q * 8;
    bf16x8 ah[4], al[4];
#pragma unroll
    for (int mt = 0; mt < 4; ++mt)
      split8(&vL[(mt * 16 + li) * 260 + e0], ah[mt], al[mt]);
#pragma unroll
    for (int nt = 0; nt < 4; ++nt) {
      int d = w * 64 + nt * 16 + li;
      const u16* bp = Wns + (size_t)kk * 131072 + (size_t)d * 256 + e0;
      bf16x8 bh = *(const bf16x8*)bp;
      bf16x8 bl = *(const bf16x8*)(bp + 65536);
#pragma unroll
      for (int mt = 0; mt < 4; ++mt) {
        wacc[mt][nt] = mfma(al[mt], bh, wacc[mt][nt]);
        wacc[mt][nt] = mfma(ah[mt], bl, wacc[mt][nt]);
        wacc[mt][nt] = mfma(ah[mt], bh, wacc[mt][nt]);
      }
    }
  }
#pragma unroll
  for (int mt = 0; mt < 4; ++mt)
#pragma unroll
    for (int r = 0; r < 4; ++r) {
      int a = mt * 16 + q * 4 + r;
#pragma unroll
      for (int nt = 0; nt < 4; ++nt)
        wv[((size_t)a * KN + kk) * 256 + w * 64 + nt * 16 + li] = wacc[mt][nt][r];
    }
}

// ================= pdlpy1 (stage1): block = a =================
// DL: dl[kk,b] = sum_d wv[kk,d] x[b,d] (m=kk wave=mt, n=b 8nt; x split shared via LDS)
// logits += dl; softmax over b -> P (LDS); PY: y[kk,d] = sum_b P[kk,b] xT[d,b]
__global__ __launch_bounds__(256, 2) void pdlpy1(
    const float* __restrict__ x,      // [64][128][256]
    const u16* __restrict__ xTs,      // [64][2][256][128]
    const float* __restrict__ wv,     // [a][64][256]
    float* __restrict__ L,            // [a][64][128]
    float* __restrict__ Y,            // [kk][a][256]
    int iter) {
  __shared__ u16 xh[128 * 40], xl[128 * 40];
  __shared__ __align__(16) float pP[64 * 132];
  const int tid = threadIdx.x;
  const int w = tid >> 6, lane = tid & 63, q = lane >> 4, li = lane & 15;
  const int a = blockIdx.x;

  f32x4 dacc[8] = {};
  for (int ks = 0; ks < 8; ++ks) {
    __syncthreads();
    for (int idx = tid; idx < 4096; idx += 256) {
      int b = idx >> 5, dl = idx & 31;
      float f = x[((size_t)a * 128 + b) * 256 + ks * 32 + dl];
      u32 hb = bf16_rne(f);
      u32 lb = bf16_rne(f - bf16_val(hb));
      xh[b * 40 + dl] = (u16)hb;
      xl[b * 40 + dl] = (u16)lb;
    }
    __syncthreads();
    bf16x8 ah, al;
    split8(wv + ((size_t)a * 64 + w * 16 + li) * 256 + ks * 32 + q * 8, ah, al);
#pragma unroll
    for (int nt = 0; nt < 8; ++nt) {
      int b = nt * 16 + li;
      bf16x8 bh = *(const bf16x8*)(xh + b * 40 + q * 8);
      bf16x8 bl = *(const bf16x8*)(xl + b * 40 + q * 8);
      dacc[nt] = mfma(al, bh, dacc[nt]);
      dacc[nt] = mfma(ah, bl, dacc[nt]);
      dacc[nt] = mfma(ah, bh, dacc[nt]);
    }
  }
  // logits + softmax per kk-row (kk = w*16 + q*4 + r; b = nt*16 + li)
#pragma unroll
  for (int r = 0; r < 4; ++r) {
    int kk = w * 16 + q * 4 + r;
    float lr[8];
    float mx = -3.0e38f;
#pragma unroll
    for (int nt = 0; nt < 8; ++nt) {
      int b = nt * 16 + li;
      float t = dacc[nt][r];
      if (iter > 0) t += L[((size_t)a * 64 + kk) * 128 + b];
      lr[nt] = t;
      mx = fmaxf(mx, t);
    }
    if (iter == 0) {
#pragma unroll
      for (int nt = 0; nt < 8; ++nt)
        L[((size_t)a * 64 + kk) * 128 + nt * 16 + li] = lr[nt];
    }
    mx = fmaxf(mx, __shfl_xor(mx, 1));
    mx = fmaxf(mx, __shfl_xor(mx, 2));
    mx = fmaxf(mx, __shfl_xor(mx, 4));
    mx = fmaxf(mx, __shfl_xor(mx, 8));
    float zs = 0.f;
#pragma unroll
    for (int nt = 0; nt < 8; ++nt) { lr[nt] = expf(lr[nt] - mx); zs += lr[nt]; }
    zs += __shfl_xor(zs, 1);
    zs += __shfl_xor(zs, 2);
    zs += __shfl_xor(zs, 4);
    zs += __shfl_xor(zs, 8);
    float inv = 1.0f / zs;
#pragma unroll
    for (int nt = 0; nt < 8; ++nt)
      pP[kk * 132 + nt * 16 + li] = lr[nt] * inv;
  }
  __syncthreads();
  // PY: m=kk (4mt), n=d (wave = d-quarter, 4nt), k=b (4 ks)
  f32x4 yacc[4][4] = {};
  for (int ks = 0; ks < 4; ++ks) {
    const int b0 = ks * 32 + q * 8;
    bf16x8 ph[4], pl[4];
#pragma unroll
    for (int mt = 0; mt < 4; ++mt)
      split8(&pP[(mt * 16 + li) * 132 + b0], ph[mt], pl[mt]);
#pragma unroll
    for (int nt = 0; nt < 4; ++nt) {
      int d = w * 64 + nt * 16 + li;
      const u16* bp = xTs + (size_t)a * 65536 + (size_t)d * 128 + b0;
      bf16x8 bh = *(const bf16x8*)bp;
      bf16x8 bl = *(const bf16x8*)(bp + 32768);
#pragma unroll
      for (int mt = 0; mt < 4; ++mt) {
        yacc[mt][nt] = mfma(pl[mt], bh, yacc[mt][nt]);
        yacc[mt][nt] = mfma(ph[mt], bl, yacc[mt][nt]);
        yacc[mt][nt] = mfma(ph[mt], bh, yacc[mt][nt]);
      }
    }
  }
#pragma unroll
  for (int mt = 0; mt < 4; ++mt)
#pragma unroll
    for (int r = 0; r < 4; ++r) {
      int kk = mt * 16 + q * 4 + r;
#pragma unroll
      for (int nt = 0; nt < 4; ++nt)
        Y[((size_t)kk * 64 + a) * 256 + w * 64 + nt * 16 + li] = yacc[mt][nt][r];
    }
}

// ================= pdlpy2 (stage2): block = a =================
// DL: m=b (4mt), n=kk (wave 0/1), k=d; softmax over b in-wave (q-butterfly).
// PY: m=kk (mt=w&1), n=d (half = w>>1), k=h (2 ks).
__global__ __launch_bounds__(256, 2) void pdlpy2(
    const float* __restrict__ o1,     // [64][64][256]
    const u16* __restrict__ o1Ts,     // [64][2][256][64]
    const float* __restrict__ wv,     // [a][32][256]
    float* __restrict__ L,            // [a][32][64]
    float* __restrict__ Y,            // [kk][a][256]
    int iter) {
  __shared__ __align__(16) float pP[32 * 68];
  const int tid = threadIdx.x;
  const int w = tid >> 6, lane = tid & 63, q = lane >> 4, li = lane & 15;
  const int a = blockIdx.x;

  if (w < 2) {
    f32x4 dacc[4] = {};
    for (int ks = 0; ks < 8; ++ks) {
      const int d0 = ks * 32 + q * 8;
      bf16x8 bh, bl;
      split8(wv + ((size_t)a * 32 + w * 16 + li) * 256 + d0, bh, bl);
#pragma unroll
      for (int mt = 0; mt < 4; ++mt) {
        bf16x8 ah, al;
        split8(o1 + ((size_t)a * 64 + mt * 16 + li) * 256 + d0, ah, al);
        dacc[mt] = mfma(al, bh, dacc[mt]);
        dacc[mt] = mfma(ah, bl, dacc[mt]);
        dacc[mt] = mfma(ah, bh, dacc[mt]);
      }
    }
    int kk = w * 16 + li;
    float lr[4][4];
    float mx = -3.0e38f;
#pragma unroll
    for (int mt = 0; mt < 4; ++mt)
#pragma unroll
      for (int r = 0; r < 4; ++r) {
        int b = mt * 16 + q * 4 + r;
        float t = dacc[mt][r];
        if (iter > 0) t += L[((size_t)a * 32 + kk) * 64 + b];
        lr[mt][r] = t;
        mx = fmaxf(mx, t);
      }
    if (iter == 0) {
#pragma unroll
      for (int mt = 0; mt < 4; ++mt)
#pragma unroll
        for (int r = 0; r < 4; ++r)
          L[((size_t)a * 32 + kk) * 64 + mt * 16 + q * 4 + r] = lr[mt][r];
    }
    mx = fmaxf(mx, __shfl_xor(mx, 16));
    mx = fmaxf(mx, __shfl_xor(mx, 32));
    float zs = 0.f;
#pragma unroll
    for (int mt = 0; mt < 4; ++mt)
#pragma unroll
      for (int r = 0; r < 4; ++r) { lr[mt][r] = expf(lr[mt][r] - mx); zs += lr[mt][r]; }
    zs += __shfl_xor(zs, 16);
    zs += __shfl_xor(zs, 32);
    float inv = 1.0f / zs;
#pragma unroll
    for (int mt = 0; mt < 4; ++mt)
#pragma unroll
      for (int r = 0; r < 4; ++r)
        pP[kk * 68 + mt * 16 + q * 4 + r] = lr[mt][r] * inv;
  }
  __syncthreads();
  // PY
  f32x4 yacc[8] = {};
  const int mt = w & 1, nh = w >> 1;
  for (int ks = 0; ks < 2; ++ks) {
    const int b0 = ks * 32 + q * 8;
    bf16x8 ph, pl;
    split8(&pP[(mt * 16 + li) * 68 + b0], ph, pl);
#pragma unroll
    for (int nt = 0; nt < 8; ++nt) {
      int d = nh * 128 + nt * 16 + li;
      const u16* bp = o1Ts + (size_t)a * 32768 + (size_t)d * 64 + b0;
      bf16x8 bh = *(const bf16x8*)bp;
      bf16x8 bl = *(const bf16x8*)(bp + 16384);
      yacc[nt] = mfma(pl, bh, yacc[nt]);
      yacc[nt] = mfma(ph, bl, yacc[nt]);
      yacc[nt] = mfma(ph, bh, yacc[nt]);
    }
  }
#pragma unroll
  for (int r = 0; r < 4; ++r) {
    int kk = mt * 16 + q * 4 + r;
#pragma unroll
    for (int nt = 0; nt < 8; ++nt)
      Y[((size_t)kk * 64 + a) * 256 + nh * 128 + nt * 16 + li] = yacc[nt][r];
  }
}

extern "C" void kernel_launch(void* const* d_in, const int* in_sizes, int n_in,
                              void* d_out, int out_size, void* d_ws, size_t ws_size,
                              hipStream_t stream) {
  const float* x  = (const float*)d_in[0];   // [64][128][256]
  const float* w1 = (const float*)d_in[1];   // [64][256][256]
  const float* wc = (const float*)d_in[2];   // [32][256][256]
  float* out = (float*)d_out;                // [32][64][256]

  char* ws = (char*)d_ws;
  u16*   W1ts = (u16*)(ws);                     // 16 MB  [64][2][256e][256d]
  u16*   W1ns = (u16*)(ws + (16ull << 20));     // 16 MB  [64][2][256d][256e]
  u16*   xTs  = (u16*)(ws + (32ull << 20));     //  8 MB  [64][2][256d][128b]
  float* Yb   = (float*)(ws + (40ull << 20));   //  4 MB  [kk][a][256]
  float* WVb  = (float*)(ws + (44ull << 20));   //  4 MB  [a][KN][256]
  float* Lb   = (float*)(ws + (48ull << 20));   //  2 MB  [a][KN][R]
  float* o1f  = (float*)(ws + (50ull << 20));   //  4 MB  [a][64][256]
  float* y0   = (float*)(ws + (54ull << 20));   // 64 KB
  // stage2 overlays (stage1 weight regions dead by then)
  u16*   Wcts = (u16*)(ws);                     //  8 MB
  u16*   Wcns = (u16*)(ws + (8ull << 20));      //  8 MB
  u16*   o1Ts = (u16*)(ws + (16ull << 20));     //  4 MB  [64][2][256d][64h]

  // ---- stage 1 prep ----
  split_transpose256<<<dim3(8, 8, 64), dim3(32, 8), 0, stream>>>(w1, W1ts);
  split_pairs<<<4096, 256, 0, stream>>>(w1, W1ns, 1048576, 16384);
  split_transpose_rect<<<dim3(8, 4, 64), dim3(32, 8), 0, stream>>>(x, xTs, 128);
  mean_rows<<<64, 256, 0, stream>>>(x, y0, 128, 1.0f / 128.0f);
  // ---- stage 1 routing ----
  pswv<64><<<64, 256, 0, stream>>>(Yb, y0, W1ts, W1ns, WVb, o1f, 0, 1);
  pdlpy1<<<64, 256, 0, stream>>>(x, xTs, WVb, Lb, Yb, 0);
  pswv<64><<<64, 256, 0, stream>>>(Yb, y0, W1ts, W1ns, WVb, o1f, 1, 1);
  pdlpy1<<<64, 256, 0, stream>>>(x, xTs, WVb, Lb, Yb, 1);
  pswv<64><<<64, 256, 0, stream>>>(Yb, y0, W1ts, W1ns, WVb, o1f, 2, 1);
  // ---- stage 2 prep ----
  split_transpose256<<<dim3(8, 8, 32), dim3(32, 8), 0, stream>>>(wc, Wcts);
  split_pairs<<<2048, 256, 0, stream>>>(wc, Wcns, 524288, 16384);
  split_transpose_rect<<<dim3(8, 2, 64), dim3(32, 8), 0, stream>>>(o1f, o1Ts, 64);
  mean_rows<<<64, 256, 0, stream>>>(o1f, y0, 64, 1.0f / 64.0f);
  // ---- stage 2 routing ----
  pswv<32><<<32, 256, 0, stream>>>(Yb, y0, Wcts, Wcns, WVb, out, 0, 2);
  pdlpy2<<<64, 256, 0, stream>>>(o1f, o1Ts, WVb, Lb, Yb, 0);
  pswv<32><<<32, 256, 0, stream>>>(Yb, y0, Wcts, Wcns, WVb, out, 1, 2);
  pdlpy2<<<64, 256, 0, stream>>>(o1f, o1Ts, WVb, Lb, Yb, 1);
  pswv<32><<<32, 256, 0, stream>>>(Yb, y0, Wcts, Wcns, WVb, out, 2, 2);
}